// Round 4
// baseline (138.164 us; speedup 1.0000x reference)
//
#include <hip/hip_runtime.h>
#include <math.h>

#define B_    4
#define CIN_  64
#define COUT_ 64
#define N_    32768
#define S_    8192

typedef __attribute__((ext_vector_type(2))) float f32x2;
typedef __attribute__((ext_vector_type(4))) float f32x4v;
typedef __attribute__((ext_vector_type(8))) short short8;
typedef __attribute__((ext_vector_type(8))) unsigned short ushort8;
typedef __attribute__((ext_vector_type(4))) unsigned short ushort4v;

// packed f32 FMA: acc[i] += w[i]*m[i], w is wave-uniform (SGPR pair)
#define PK_FMA_SV(acc, w, m) \
    asm("v_pk_fma_f32 %0, %1, %2, %0" : "+v"(acc) : "s"(w), "v"(m))
#define PK_FMA_VV(acc, a, b) \
    asm("v_pk_fma_f32 %0, %1, %2, %0" : "+v"(acc) : "v"(a), "v"(b))

static __device__ __forceinline__ unsigned short f2bf(float x) {
    unsigned u = __float_as_uint(x);
    u += 0x7fffu + ((u >> 16) & 1u);
    return (unsigned short)(u >> 16);
}

// ---------------------------------------------------------------------------
// Kernel A1: transpose x [B][64][N] -> xT [B][N][64]
// ---------------------------------------------------------------------------
__global__ __launch_bounds__(256) void transpose_x_kernel(
    const float* __restrict__ x, float* __restrict__ xT)
{
    __shared__ float tile[64][65];
    const int b  = blockIdx.y;
    const int n0 = blockIdx.x * 64;
    const int tx = threadIdx.x & 63;
    const int ty = threadIdx.x >> 6;

    const float* xb = x + (size_t)b * CIN_ * N_;
    #pragma unroll
    for (int c = ty; c < 64; c += 4)
        tile[c][tx] = xb[(size_t)c * N_ + n0 + tx];
    __syncthreads();
    float* xTb = xT + ((size_t)b * N_ + n0) * 64;
    #pragma unroll
    for (int nn = ty; nn < 64; nn += 4)
        xTb[(size_t)nn * 64 + tx] = tile[tx][nn];
}

// ---------------------------------------------------------------------------
// Kernel A2: pos [B][3][N] -> posT [B][N][4]
// ---------------------------------------------------------------------------
__global__ __launch_bounds__(256) void post_kernel(
    const float* __restrict__ pos, float* __restrict__ posT)
{
    const int b = blockIdx.y;
    const int n = blockIdx.x * 256 + threadIdx.x;
    const float* pb = pos + (size_t)b * 3 * N_;
    float4 v = make_float4(pb[n], pb[N_ + n], pb[2 * N_ + n], 0.0f);
    *(float4*)&posT[((size_t)b * N_ + n) * 4] = v;
}

// ---------------------------------------------------------------------------
// Kernel A3: wcv f32 [64][1024] -> bf16
// ---------------------------------------------------------------------------
__global__ __launch_bounds__(256) void wcvb_kernel(
    const float* __restrict__ wcv, unsigned short* __restrict__ wcvB)
{
    const int i = (blockIdx.x * 256 + threadIdx.x) * 4;
    float4 v = *(const float4*)&wcv[i];
    ushort4v o;
    o[0] = f2bf(v.x); o[1] = f2bf(v.y); o[2] = f2bf(v.z); o[3] = f2bf(v.w);
    *(ushort4v*)&wcvB[i] = o;
}

// ---------------------------------------------------------------------------
// Kernel B: fc pipeline (packed f32 FMA, shfl_xor maxpool) then feats
// (packed f32), feats written bf16 [s][c*16+k].
// ---------------------------------------------------------------------------
__global__ __launch_bounds__(256) void fka_feats_kernel(
    const float* __restrict__ posT, const float* __restrict__ sup,
    const int*   __restrict__ nbr, const float* __restrict__ radius,
    const float* __restrict__ w1,  const float* __restrict__ w2,
    const float* __restrict__ w3,  const float* __restrict__ xT,
    unsigned short* __restrict__ featsB, int s_base, int S_chunk)
{
    __shared__ float m3s[8][32][20];
    __shared__ int   idxs[8][32];

    const int b  = blockIdx.y;
    const int t  = threadIdx.x;
    const int g  = t >> 5;
    const int n  = t & 31;
    const int sl = blockIdx.x * 8 + g;
    const int s  = s_base + sl;

    // ---- phase 1: fc pipeline (lane = neighbor) ----
    const int raw   = nbr[(((size_t)b * S_ + s) << 5) + n];
    const bool valid = raw > -1;
    const int id    = valid ? raw : 0;

    unsigned long long bal = __ballot(valid);
    unsigned bits = (unsigned)(bal >> (t & 32));
    const float nrm = sqrtf((float)__popc(bits));
    float dw = valid ? (1.0f / fmaxf(nrm, 1e-12f)) : 0.0f;

    const float4 pg = *(const float4*)&posT[((size_t)b * N_ + id) * 4];
    float px = pg.x - sup[(size_t)(b * 3 + 0) * S_ + s];
    float py = pg.y - sup[(size_t)(b * 3 + 1) * S_ + s];
    float pz = pg.z - sup[(size_t)(b * 3 + 2) * S_ + s];
    if (isinf(px)) dw = 0.0f;
    px = (isnan(px) || isinf(px)) ? 0.0f : px;
    py = (isnan(py) || isinf(py)) ? 0.0f : py;
    pz = (isnan(pz) || isinf(pz)) ? 0.0f : pz;
    const float inv_r = 1.0f / radius[0];
    px *= inv_r; py *= inv_r; pz *= inv_r;

    f32x2 m1[8], mp1[8], m2[8], mp2[8];
    float m3[16];

    // fc1 (scalar, small)
    #pragma unroll
    for (int k = 0; k < 16; ++k) {
        float v = w1[k * 3 + 0] * px + w1[k * 3 + 1] * py + w1[k * 3 + 2] * pz;
        m1[k >> 1][k & 1] = fmaxf(v, 0.0f) * dw;
    }
    // maxpool over 32 lanes (known-good shfl_xor butterfly)
    #pragma unroll
    for (int k = 0; k < 16; ++k) {
        float v = m1[k >> 1][k & 1];
        #pragma unroll
        for (int off = 16; off; off >>= 1)
            v = fmaxf(v, __shfl_xor(v, off, 32));
        mp1[k >> 1][k & 1] = v;
    }
    // fc2 (packed f32, uniform weights via SGPR pair)
    #pragma unroll
    for (int k = 0; k < 16; ++k) {
        const f32x2* wr = (const f32x2*)(w2 + k * 32);
        f32x2 acc = {0.0f, 0.0f};
        #pragma unroll
        for (int j = 0; j < 8; ++j) PK_FMA_SV(acc, wr[j], m1[j]);
        #pragma unroll
        for (int j = 0; j < 8; ++j) PK_FMA_SV(acc, wr[8 + j], mp1[j]);
        float v = acc[0] + acc[1];
        m2[k >> 1][k & 1] = fmaxf(v, 0.0f) * dw;
    }
    #pragma unroll
    for (int k = 0; k < 16; ++k) {
        float v = m2[k >> 1][k & 1];
        #pragma unroll
        for (int off = 16; off; off >>= 1)
            v = fmaxf(v, __shfl_xor(v, off, 32));
        mp2[k >> 1][k & 1] = v;
    }
    // fc3 (packed f32)
    #pragma unroll
    for (int k = 0; k < 16; ++k) {
        const f32x2* wr = (const f32x2*)(w3 + k * 32);
        f32x2 acc = {0.0f, 0.0f};
        #pragma unroll
        for (int j = 0; j < 8; ++j) PK_FMA_SV(acc, wr[j], m2[j]);
        #pragma unroll
        for (int j = 0; j < 8; ++j) PK_FMA_SV(acc, wr[8 + j], mp2[j]);
        float v = acc[0] + acc[1];
        m3[k] = fmaxf(v, 0.0f) * dw;
    }

    idxs[g][n] = id;
    float* mrow = &m3s[g][n][0];
    *(float4*)(mrow +  0) = make_float4(m3[0],  m3[1],  m3[2],  m3[3]);
    *(float4*)(mrow +  4) = make_float4(m3[4],  m3[5],  m3[6],  m3[7]);
    *(float4*)(mrow +  8) = make_float4(m3[8],  m3[9],  m3[10], m3[11]);
    *(float4*)(mrow + 12) = make_float4(m3[12], m3[13], m3[14], m3[15]);
    __syncthreads();

    // ---- phase 2: feats (lane = channel, packed f32), 2 points per wave ----
    const int wv = t >> 6;
    const int c  = t & 63;
    const size_t xTb = (size_t)b * N_ * 64;

    for (int pp = 0; pp < 2; ++pp) {
        const int p = wv * 2 + pp;
        const int* ids = idxs[p];
        f32x2 f[8];
        #pragma unroll
        for (int q = 0; q < 8; ++q) f[q] = (f32x2){0.0f, 0.0f};

        #pragma unroll 4
        for (int nn = 0; nn < 32; ++nn) {
            const float xv = xT[xTb + ((size_t)ids[nn] << 6) + c];
            f32x2 xv2; xv2[0] = xv; xv2[1] = xv;
            const f32x4v* mrow4 = (const f32x4v*)&m3s[p][nn][0];
            const f32x4v a = mrow4[0], bq = mrow4[1], cq = mrow4[2], dq = mrow4[3];
            f32x2 p0 = {a[0],  a[1]},  p1 = {a[2],  a[3]};
            f32x2 p2 = {bq[0], bq[1]}, p3 = {bq[2], bq[3]};
            f32x2 p4 = {cq[0], cq[1]}, p5 = {cq[2], cq[3]};
            f32x2 p6 = {dq[0], dq[1]}, p7 = {dq[2], dq[3]};
            PK_FMA_VV(f[0], p0, xv2); PK_FMA_VV(f[1], p1, xv2);
            PK_FMA_VV(f[2], p2, xv2); PK_FMA_VV(f[3], p3, xv2);
            PK_FMA_VV(f[4], p4, xv2); PK_FMA_VV(f[5], p5, xv2);
            PK_FMA_VV(f[6], p6, xv2); PK_FMA_VV(f[7], p7, xv2);
        }

        ushort8 lo, hi;
        #pragma unroll
        for (int q = 0; q < 4; ++q) {
            lo[2*q]   = f2bf(f[q][0]);     lo[2*q+1] = f2bf(f[q][1]);
            hi[2*q]   = f2bf(f[4+q][0]);   hi[2*q+1] = f2bf(f[4+q][1]);
        }
        unsigned short* fb = featsB
            + (((size_t)b * S_chunk + (size_t)blockIdx.x * 8 + p) << 10) + (c << 4);
        *(ushort8*)(fb)     = lo;
        *(ushort8*)(fb + 8) = hi;
    }
}

// ---------------------------------------------------------------------------
// Kernel C: out = wcvB[64][1024] x featsB[s][1024]^T via bf16 MFMA.
// ---------------------------------------------------------------------------
__global__ __launch_bounds__(512) void fka_out_mfma(
    const unsigned short* __restrict__ wcvB,
    const unsigned short* __restrict__ featsB,
    const float* __restrict__ sup,
    float* __restrict__ out, int s_base, int S_chunk)
{
    typedef __attribute__((ext_vector_type(4))) float f32x4a;
    const int b    = blockIdx.y;
    const int t    = threadIdx.x;
    const int wv   = t >> 6;
    const int wv_o = wv & 1;
    const int wv_s = wv >> 1;
    const int l    = t & 63;
    const int l15  = l & 15;
    const int lq   = l >> 4;
    const int kq   = lq * 8;

    const unsigned short* ap = wcvB + (size_t)(wv_o * 32 + l15) * 1024 + kq;
    const unsigned short* bp = featsB
        + ((size_t)b * S_chunk + (size_t)blockIdx.x * 128 + wv_s * 32 + l15) * 1024 + kq;

    f32x4a acc[2][2];
    #pragma unroll
    for (int i = 0; i < 2; ++i)
        #pragma unroll
        for (int j = 0; j < 2; ++j) acc[i][j] = (f32x4a){0.f, 0.f, 0.f, 0.f};

    #pragma unroll 4
    for (int ks = 0; ks < 32; ++ks) {
        const int k0 = ks * 32;
        short8 a0 = *(const short8*)(ap + k0);
        short8 a1 = *(const short8*)(ap + 16 * 1024 + k0);
        short8 b0 = *(const short8*)(bp + k0);
        short8 b1 = *(const short8*)(bp + 16 * 1024 + k0);
        acc[0][0] = __builtin_amdgcn_mfma_f32_16x16x32_bf16(a0, b0, acc[0][0], 0, 0, 0);
        acc[0][1] = __builtin_amdgcn_mfma_f32_16x16x32_bf16(a0, b1, acc[0][1], 0, 0, 0);
        acc[1][0] = __builtin_amdgcn_mfma_f32_16x16x32_bf16(a1, b0, acc[1][0], 0, 0, 0);
        acc[1][1] = __builtin_amdgcn_mfma_f32_16x16x32_bf16(a1, b1, acc[1][1], 0, 0, 0);
    }

    #pragma unroll
    for (int sc = 0; sc < 2; ++sc) {
        const int s = s_base + blockIdx.x * 128 + wv_s * 32 + sc * 16 + l15;
        const bool infs = isinf(sup[(size_t)b * 3 * S_ + s]);
        #pragma unroll
        for (int oc = 0; oc < 2; ++oc)
            #pragma unroll
            for (int r = 0; r < 4; ++r) {
                const int o = wv_o * 32 + oc * 16 + lq * 4 + r;
                out[((size_t)b * COUT_ + o) * S_ + s] = infs ? INFINITY : acc[oc][sc][r];
            }
    }
}

// ---------------------------------------------------------------------------
extern "C" void kernel_launch(void* const* d_in, const int* in_sizes, int n_in,
                              void* d_out, int out_size, void* d_ws, size_t ws_size,
                              hipStream_t stream)
{
    const float* x   = (const float*)d_in[0];
    const float* pos = (const float*)d_in[1];
    const float* sup = (const float*)d_in[2];
    const int*   nbr = (const int*)d_in[3];
    const float* rad = (const float*)d_in[4];
    const float* w1  = (const float*)d_in[5];
    const float* w2  = (const float*)d_in[6];
    const float* w3  = (const float*)d_in[7];
    const float* wcv = (const float*)d_in[8];
    float* out = (float*)d_out;

    char* p = (char*)d_ws;
    float* xT = (float*)p;                 p += (size_t)B_ * N_ * 64 * sizeof(float);
    float* posT = (float*)p;               p += (size_t)B_ * N_ * 4 * sizeof(float);
    unsigned short* wcvB = (unsigned short*)p; p += (size_t)COUT_ * 1024 * sizeof(unsigned short);
    unsigned short* featsB = (unsigned short*)p;
    const size_t used = (size_t)(p - (char*)d_ws);
    const size_t avail = (ws_size > used) ? (ws_size - used) : 0;

    int S_chunk = S_;
    while (S_chunk > 128 && (size_t)B_ * (size_t)S_chunk * 1024 * 2 > avail)
        S_chunk >>= 1;

    transpose_x_kernel<<<dim3(N_ / 64, B_), 256, 0, stream>>>(x, xT);
    post_kernel<<<dim3(N_ / 256, B_), 256, 0, stream>>>(pos, posT);
    wcvb_kernel<<<dim3(64), 256, 0, stream>>>(wcv, wcvB);

    for (int sb = 0; sb < S_; sb += S_chunk) {
        fka_feats_kernel<<<dim3(S_chunk / 8, B_), 256, 0, stream>>>(
            posT, sup, nbr, rad, w1, w2, w3, xT, featsB, sb, S_chunk);
        fka_out_mfma<<<dim3(S_chunk / 128, B_), 512, 0, stream>>>(
            wcvB, featsB, sup, out, sb, S_chunk);
    }
}

// Round 5
// 113.906 us; speedup vs baseline: 1.2130x; 1.2130x over previous
//
#include <hip/hip_runtime.h>
#include <math.h>

#define B_    4
#define CIN_  64
#define COUT_ 64
#define N_    32768
#define S_    8192

typedef __attribute__((ext_vector_type(8))) short short8;
typedef __attribute__((ext_vector_type(4))) float f32x4a;
typedef __attribute__((ext_vector_type(4))) unsigned short ushort4v;

static __device__ __forceinline__ unsigned short f2bf(float x) {
    unsigned u = __float_as_uint(x);
    u += 0x7fffu + ((u >> 16) & 1u);
    return (unsigned short)(u >> 16);
}
static __device__ __forceinline__ unsigned pack2bf(float a, float b) {
    return (unsigned)f2bf(a) | ((unsigned)f2bf(b) << 16);
}

// ---------------------------------------------------------------------------
// Kernel A1: transpose x [B][64][N] -> xT [B][N][64]
// ---------------------------------------------------------------------------
__global__ __launch_bounds__(256) void transpose_x_kernel(
    const float* __restrict__ x, float* __restrict__ xT)
{
    __shared__ float tile[64][65];
    const int b  = blockIdx.y;
    const int n0 = blockIdx.x * 64;
    const int tx = threadIdx.x & 63;
    const int ty = threadIdx.x >> 6;

    const float* xb = x + (size_t)b * CIN_ * N_;
    #pragma unroll
    for (int c = ty; c < 64; c += 4)
        tile[c][tx] = xb[(size_t)c * N_ + n0 + tx];
    __syncthreads();
    float* xTb = xT + ((size_t)b * N_ + n0) * 64;
    #pragma unroll
    for (int nn = ty; nn < 64; nn += 4)
        xTb[(size_t)nn * 64 + tx] = tile[tx][nn];
}

// ---------------------------------------------------------------------------
// Kernel A2: pos [B][3][N] -> posT [B][N][4]
// ---------------------------------------------------------------------------
__global__ __launch_bounds__(256) void post_kernel(
    const float* __restrict__ pos, float* __restrict__ posT)
{
    const int b = blockIdx.y;
    const int n = blockIdx.x * 256 + threadIdx.x;
    const float* pb = pos + (size_t)b * 3 * N_;
    float4 v = make_float4(pb[n], pb[N_ + n], pb[2 * N_ + n], 0.0f);
    *(float4*)&posT[((size_t)b * N_ + n) * 4] = v;
}

// ---------------------------------------------------------------------------
// Kernel A3: wcv f32 [o][c][k] -> wcvB bf16 [o][k*64+c]  (k-major, matches
// the k-major feats layout so the out-GEMM contraction orders align)
// ---------------------------------------------------------------------------
__global__ __launch_bounds__(256) void wcvb_kernel(
    const float* __restrict__ wcv, unsigned short* __restrict__ wcvB)
{
    const int i = blockIdx.x * 256 + threadIdx.x;   // over 64*1024
    const int o   = i >> 10;
    const int rem = i & 1023;
    const int k   = rem >> 6;
    const int c   = rem & 63;
    wcvB[i] = f2bf(wcv[(size_t)o * 1024 + c * 16 + k]);
}

// ---------------------------------------------------------------------------
// Kernel B: phase 1 = fc pipeline (scalar f32, shfl_xor maxpool), m3 written
// to LDS as bf16 in MFMA B-fragment layout (row-rotated for bank spread).
// phase 2 = feats via mfma_f32_16x16x32_bf16: per point 4 c-tile MFMAs,
// feats written bf16 k-major [s][k*64+c].
// ---------------------------------------------------------------------------
__global__ __launch_bounds__(256) void fka_feats_kernel(
    const float* __restrict__ posT, const float* __restrict__ sup,
    const int*   __restrict__ nbr, const float* __restrict__ radius,
    const float* __restrict__ w1,  const float* __restrict__ w2,
    const float* __restrict__ w3,  const float* __restrict__ xT,
    unsigned short* __restrict__ featsB, int s_base, int S_chunk)
{
    // [p][hi(4)][row(16)][j(8)] bf16 ; row = (k + hi + p) & 15
    __shared__ unsigned short m3B[8 * 512];
    __shared__ int idxs[8][32];

    const int b  = blockIdx.y;
    const int t  = threadIdx.x;
    const int g  = t >> 5;
    const int n  = t & 31;
    const int sl = blockIdx.x * 8 + g;
    const int s  = s_base + sl;

    // ---- phase 1: fc pipeline (lane = neighbor), scalar f32 ----
    const int raw    = nbr[(((size_t)b * S_ + s) << 5) + n];
    const bool valid = raw > -1;
    const int id     = valid ? raw : 0;

    unsigned long long bal = __ballot(valid);
    unsigned bits = (unsigned)(bal >> (t & 32));
    const float nrm = sqrtf((float)__popc(bits));
    float dw = valid ? (1.0f / fmaxf(nrm, 1e-12f)) : 0.0f;

    const float4 pg = *(const float4*)&posT[((size_t)b * N_ + id) * 4];
    float px = pg.x - sup[(size_t)(b * 3 + 0) * S_ + s];
    float py = pg.y - sup[(size_t)(b * 3 + 1) * S_ + s];
    float pz = pg.z - sup[(size_t)(b * 3 + 2) * S_ + s];
    if (isinf(px)) dw = 0.0f;
    px = (isnan(px) || isinf(px)) ? 0.0f : px;
    py = (isnan(py) || isinf(py)) ? 0.0f : py;
    pz = (isnan(pz) || isinf(pz)) ? 0.0f : pz;
    const float inv_r = 1.0f / radius[0];
    px *= inv_r; py *= inv_r; pz *= inv_r;

    float m1[16], mp1[16], m2[16], mp2[16], m3[16];

    #pragma unroll
    for (int k = 0; k < 16; ++k) {
        float v = w1[k * 3 + 0] * px + w1[k * 3 + 1] * py + w1[k * 3 + 2] * pz;
        m1[k] = fmaxf(v, 0.0f) * dw;
    }
    #pragma unroll
    for (int k = 0; k < 16; ++k) {
        float v = m1[k];
        #pragma unroll
        for (int off = 16; off; off >>= 1)
            v = fmaxf(v, __shfl_xor(v, off, 32));
        mp1[k] = v;
    }
    #pragma unroll
    for (int k = 0; k < 16; ++k) {
        const float* wr = &w2[k * 32];
        float v = 0.0f;
        #pragma unroll
        for (int j = 0; j < 16; ++j) v = fmaf(wr[j], m1[j], v);
        #pragma unroll
        for (int j = 0; j < 16; ++j) v = fmaf(wr[16 + j], mp1[j], v);
        m2[k] = fmaxf(v, 0.0f) * dw;
    }
    #pragma unroll
    for (int k = 0; k < 16; ++k) {
        float v = m2[k];
        #pragma unroll
        for (int off = 16; off; off >>= 1)
            v = fmaxf(v, __shfl_xor(v, off, 32));
        mp2[k] = v;
    }
    #pragma unroll
    for (int k = 0; k < 16; ++k) {
        const float* wr = &w3[k * 32];
        float v = 0.0f;
        #pragma unroll
        for (int j = 0; j < 16; ++j) v = fmaf(wr[j], m2[j], v);
        #pragma unroll
        for (int j = 0; j < 16; ++j) v = fmaf(wr[16 + j], mp2[j], v);
        m3[k] = fmaxf(v, 0.0f) * dw;
    }

    idxs[g][n] = id;
    {
        const int hi = n >> 3, jj = n & 7;
        unsigned short* base = &m3B[g * 512 + hi * 128 + jj];
        #pragma unroll
        for (int k = 0; k < 16; ++k) {
            const int row = (k + hi + g) & 15;
            base[row * 8] = f2bf(m3[k]);
        }
    }
    __syncthreads();

    // ---- phase 2: feats via MFMA (2 points per wave) ----
    const int wv  = t >> 6;
    const int l   = t & 63;
    const int hi2 = l >> 4;
    const int k15 = l & 15;
    const float* xb = xT + (size_t)b * N_ * 64;

    for (int pp = 0; pp < 2; ++pp) {
        const int p = wv * 2 + pp;

        int ids8[8];
        #pragma unroll
        for (int j = 0; j < 8; ++j) ids8[j] = idxs[p][hi2 * 8 + j];

        const int brow = (k15 + hi2 + p) & 15;
        short8 bfrag = *(const short8*)&m3B[p * 512 + hi2 * 128 + brow * 8];

        f32x4a acc[4];
        #pragma unroll
        for (int ct = 0; ct < 4; ++ct) acc[ct] = (f32x4a){0.f, 0.f, 0.f, 0.f};

        #pragma unroll
        for (int ct = 0; ct < 4; ++ct) {
            float xv[8];
            #pragma unroll
            for (int j = 0; j < 8; ++j)
                xv[j] = xb[((size_t)ids8[j] << 6) + ct * 16 + k15];
            union { unsigned short u[8]; short8 v; } A;
            #pragma unroll
            for (int j = 0; j < 8; ++j) A.u[j] = f2bf(xv[j]);
            acc[ct] = __builtin_amdgcn_mfma_f32_16x16x32_bf16(A.v, bfrag, acc[ct], 0, 0, 0);
        }

        // acc[ct][r] = feats[c = ct*16 + hi2*4 + r][k = k15]; store k-major
        unsigned short* fb = featsB
            + ((size_t)b * S_chunk + (size_t)blockIdx.x * 8 + p) * 1024;
        #pragma unroll
        for (int ct = 0; ct < 4; ++ct) {
            uint2 val;
            val.x = pack2bf(acc[ct][0], acc[ct][1]);
            val.y = pack2bf(acc[ct][2], acc[ct][3]);
            *(uint2*)&fb[k15 * 64 + ct * 16 + hi2 * 4] = val;
        }
    }
}

// ---------------------------------------------------------------------------
// Kernel C: out = wcvB[64][1024] x featsB[s][1024]^T via bf16 MFMA.
// (contraction dim is k-major on both operands)
// ---------------------------------------------------------------------------
__global__ __launch_bounds__(512) void fka_out_mfma(
    const unsigned short* __restrict__ wcvB,
    const unsigned short* __restrict__ featsB,
    const float* __restrict__ sup,
    float* __restrict__ out, int s_base, int S_chunk)
{
    const int b    = blockIdx.y;
    const int t    = threadIdx.x;
    const int wv   = t >> 6;
    const int wv_o = wv & 1;
    const int wv_s = wv >> 1;
    const int l    = t & 63;
    const int l15  = l & 15;
    const int lq   = l >> 4;
    const int kq   = lq * 8;

    const unsigned short* ap = wcvB + (size_t)(wv_o * 32 + l15) * 1024 + kq;
    const unsigned short* bp = featsB
        + ((size_t)b * S_chunk + (size_t)blockIdx.x * 128 + wv_s * 32 + l15) * 1024 + kq;

    f32x4a acc[2][2];
    #pragma unroll
    for (int i = 0; i < 2; ++i)
        #pragma unroll
        for (int j = 0; j < 2; ++j) acc[i][j] = (f32x4a){0.f, 0.f, 0.f, 0.f};

    #pragma unroll 4
    for (int ks = 0; ks < 32; ++ks) {
        const int k0 = ks * 32;
        short8 a0 = *(const short8*)(ap + k0);
        short8 a1 = *(const short8*)(ap + 16 * 1024 + k0);
        short8 b0 = *(const short8*)(bp + k0);
        short8 b1 = *(const short8*)(bp + 16 * 1024 + k0);
        acc[0][0] = __builtin_amdgcn_mfma_f32_16x16x32_bf16(a0, b0, acc[0][0], 0, 0, 0);
        acc[0][1] = __builtin_amdgcn_mfma_f32_16x16x32_bf16(a0, b1, acc[0][1], 0, 0, 0);
        acc[1][0] = __builtin_amdgcn_mfma_f32_16x16x32_bf16(a1, b0, acc[1][0], 0, 0, 0);
        acc[1][1] = __builtin_amdgcn_mfma_f32_16x16x32_bf16(a1, b1, acc[1][1], 0, 0, 0);
    }

    #pragma unroll
    for (int sc = 0; sc < 2; ++sc) {
        const int s = s_base + blockIdx.x * 128 + wv_s * 32 + sc * 16 + l15;
        const bool infs = isinf(sup[(size_t)b * 3 * S_ + s]);
        #pragma unroll
        for (int oc = 0; oc < 2; ++oc)
            #pragma unroll
            for (int r = 0; r < 4; ++r) {
                const int o = wv_o * 32 + oc * 16 + lq * 4 + r;
                out[((size_t)b * COUT_ + o) * S_ + s] = infs ? INFINITY : acc[oc][sc][r];
            }
    }
}

// ---------------------------------------------------------------------------
extern "C" void kernel_launch(void* const* d_in, const int* in_sizes, int n_in,
                              void* d_out, int out_size, void* d_ws, size_t ws_size,
                              hipStream_t stream)
{
    const float* x   = (const float*)d_in[0];
    const float* pos = (const float*)d_in[1];
    const float* sup = (const float*)d_in[2];
    const int*   nbr = (const int*)d_in[3];
    const float* rad = (const float*)d_in[4];
    const float* w1  = (const float*)d_in[5];
    const float* w2  = (const float*)d_in[6];
    const float* w3  = (const float*)d_in[7];
    const float* wcv = (const float*)d_in[8];
    float* out = (float*)d_out;

    char* p = (char*)d_ws;
    float* xT = (float*)p;                 p += (size_t)B_ * N_ * 64 * sizeof(float);
    float* posT = (float*)p;               p += (size_t)B_ * N_ * 4 * sizeof(float);
    unsigned short* wcvB = (unsigned short*)p; p += (size_t)COUT_ * 1024 * sizeof(unsigned short);
    unsigned short* featsB = (unsigned short*)p;
    const size_t used = (size_t)(p - (char*)d_ws);
    const size_t avail = (ws_size > used) ? (ws_size - used) : 0;

    int S_chunk = S_;
    while (S_chunk > 128 && (size_t)B_ * (size_t)S_chunk * 1024 * 2 > avail)
        S_chunk >>= 1;

    transpose_x_kernel<<<dim3(N_ / 64, B_), 256, 0, stream>>>(x, xT);
    post_kernel<<<dim3(N_ / 256, B_), 256, 0, stream>>>(pos, posT);
    wcvb_kernel<<<dim3(256), 256, 0, stream>>>(wcv, wcvB);

    for (int sb = 0; sb < S_; sb += S_chunk) {
        fka_feats_kernel<<<dim3(S_chunk / 8, B_), 256, 0, stream>>>(
            posT, sup, nbr, rad, w1, w2, w3, xT, featsB, sb, S_chunk);
        fka_out_mfma<<<dim3(S_chunk / 128, B_), 512, 0, stream>>>(
            wcvB, featsB, sup, out, sb, S_chunk);
    }
}

// Round 7
// 98.814 us; speedup vs baseline: 1.3982x; 1.1527x over previous
//
#include <hip/hip_runtime.h>
#include <math.h>

#define B_    4
#define CIN_  64
#define COUT_ 64
#define N_    32768
#define S_    8192

typedef __attribute__((ext_vector_type(8))) short short8;
typedef __attribute__((ext_vector_type(4))) float f32x4a;

static __device__ __forceinline__ unsigned short f2bf(float x) {
    unsigned u = __float_as_uint(x);
    u += 0x7fffu + ((u >> 16) & 1u);
    return (unsigned short)(u >> 16);
}
static __device__ __forceinline__ unsigned pack2bf(float a, float b) {
    return (unsigned)f2bf(a) | ((unsigned)f2bf(b) << 16);
}
// max with row-rotated value via DPP builtin (ctrl must be a literal -> template)
template <int CTRL>
static __device__ __forceinline__ float max_ror(float v) {
    float r = __int_as_float(__builtin_amdgcn_update_dpp(
        __float_as_int(v), __float_as_int(v), CTRL, 0xf, 0xf, false));
    return fmaxf(v, r);
}
#define ROR8 0x128
#define ROR4 0x124
#define ROR2 0x122
#define ROR1 0x121

// ---------------------------------------------------------------------------
// Kernel A1: transpose x [B][64][N] f32 -> xTB [B][N][64] bf16
// (phase-2 rounds x to bf16 before the MFMA anyway, so this is bit-identical)
// ---------------------------------------------------------------------------
__global__ __launch_bounds__(256) void transpose_x_kernel(
    const float* __restrict__ x, unsigned short* __restrict__ xTB)
{
    __shared__ float tile[64][65];
    const int b  = blockIdx.y;
    const int n0 = blockIdx.x * 64;
    const int tx = threadIdx.x & 63;
    const int ty = threadIdx.x >> 6;

    const float* xb = x + (size_t)b * CIN_ * N_;
    #pragma unroll
    for (int c = ty; c < 64; c += 4)
        tile[c][tx] = xb[(size_t)c * N_ + n0 + tx];
    __syncthreads();

    // write bf16 as ushort2 pairs: lane cp covers channels 2cp,2cp+1
    const int cp = threadIdx.x & 31;        // channel pair
    const int r0 = threadIdx.x >> 5;        // row group (8 rows)
    unsigned short* xTb = xTB + ((size_t)b * N_ + n0) * 64;
    #pragma unroll
    for (int nn = r0; nn < 64; nn += 8) {
        ushort2 v;
        v.x = f2bf(tile[2 * cp][nn]);
        v.y = f2bf(tile[2 * cp + 1][nn]);
        *(ushort2*)&xTb[(size_t)nn * 64 + 2 * cp] = v;
    }
}

// ---------------------------------------------------------------------------
// Kernel A2: pos [B][3][N] -> posT [B][N][4]
// ---------------------------------------------------------------------------
__global__ __launch_bounds__(256) void post_kernel(
    const float* __restrict__ pos, float* __restrict__ posT)
{
    const int b = blockIdx.y;
    const int n = blockIdx.x * 256 + threadIdx.x;
    const float* pb = pos + (size_t)b * 3 * N_;
    float4 v = make_float4(pb[n], pb[N_ + n], pb[2 * N_ + n], 0.0f);
    *(float4*)&posT[((size_t)b * N_ + n) * 4] = v;
}

// ---------------------------------------------------------------------------
// Kernel A3: wcv f32 [o][c][k] -> wcvB bf16 [o][k*64+c]  (k-major)
// ---------------------------------------------------------------------------
__global__ __launch_bounds__(256) void wcvb_kernel(
    const float* __restrict__ wcv, unsigned short* __restrict__ wcvB)
{
    const int i = blockIdx.x * 256 + threadIdx.x;   // over 64*1024
    const int o   = i >> 10;
    const int rem = i & 1023;
    const int k   = rem >> 6;
    const int c   = rem & 63;
    wcvB[i] = f2bf(wcv[(size_t)o * 1024 + c * 16 + k]);
}

// ---------------------------------------------------------------------------
// Kernel B: phase 1 = fc pipeline (scalar f32; DPP maxpool; cooperative
// shared mp-term through LDS). phase 2 = feats via mfma_f32_16x16x32_bf16
// with bf16 x gathers, feats written bf16 k-major [s][k*64+c].
// ---------------------------------------------------------------------------
__global__ __launch_bounds__(256) void fka_feats_kernel(
    const float* __restrict__ posT, const float* __restrict__ sup,
    const int*   __restrict__ nbr, const float* __restrict__ radius,
    const float* __restrict__ w1,  const float* __restrict__ w2,
    const float* __restrict__ w3,  const unsigned short* __restrict__ xTB,
    unsigned short* __restrict__ featsB, int s_base, int S_chunk)
{
    // m3 in MFMA B-fragment layout: [p][hi(4)][row(16)][j(8)], row=(k+hi+p)&15
    __shared__ unsigned short m3B[8 * 512];
    __shared__ int   idxs[8][32];
    __shared__ float t2s[8][16];

    const int b  = blockIdx.y;
    const int t  = threadIdx.x;
    const int g  = t >> 5;
    const int n  = t & 31;
    const int sl = blockIdx.x * 8 + g;
    const int s  = s_base + sl;

    // ---- phase 1: fc pipeline (lane = neighbor), scalar f32 ----
    const int raw    = nbr[(((size_t)b * S_ + s) << 5) + n];
    const bool valid = raw > -1;
    const int id     = valid ? raw : 0;

    unsigned long long bal = __ballot(valid);
    unsigned bits = (unsigned)(bal >> (t & 32));
    const float nrm = sqrtf((float)__popc(bits));
    float dw = valid ? (1.0f / fmaxf(nrm, 1e-12f)) : 0.0f;

    const float4 pg = *(const float4*)&posT[((size_t)b * N_ + id) * 4];
    float px = pg.x - sup[(size_t)(b * 3 + 0) * S_ + s];
    float py = pg.y - sup[(size_t)(b * 3 + 1) * S_ + s];
    float pz = pg.z - sup[(size_t)(b * 3 + 2) * S_ + s];
    if (isinf(px)) dw = 0.0f;
    px = (isnan(px) || isinf(px)) ? 0.0f : px;
    py = (isnan(py) || isinf(py)) ? 0.0f : py;
    pz = (isnan(pz) || isinf(pz)) ? 0.0f : pz;
    const float inv_r = 1.0f / radius[0];
    px *= inv_r; py *= inv_r; pz *= inv_r;

    const int kk = n & 15;      // this lane's owned k for cooperative terms

    float m1[16], mp1[16], m2[16], mp2[16], m3[16];

    // fc1
    #pragma unroll
    for (int k = 0; k < 16; ++k) {
        float v = w1[k * 3 + 0] * px + w1[k * 3 + 1] * py + w1[k * 3 + 2] * pz;
        m1[k] = fmaxf(v, 0.0f) * dw;
    }
    // maxpool over 32 lanes: shfl xor16 + DPP row_ror 8/4/2/1 (exact max)
    #pragma unroll
    for (int k = 0; k < 16; ++k) {
        float v = m1[k];
        v = fmaxf(v, __shfl_xor(v, 16, 32));
        v = max_ror<ROR8>(v); v = max_ror<ROR4>(v);
        v = max_ror<ROR2>(v); v = max_ror<ROR1>(v);
        mp1[k] = v;
    }
    // fc2: cooperative mp-term (identical across lanes of the point)
    {
        const float* wb = &w2[kk * 32 + 16];
        float pa = 0.0f, pb = 0.0f;
        #pragma unroll
        for (int j = 0; j < 8; ++j) pa = fmaf(wb[j], mp1[j], pa);
        #pragma unroll
        for (int j = 0; j < 8; ++j) pb = fmaf(wb[8 + j], mp1[8 + j], pb);
        float tp = (n & 16) ? pb : pa;
        tp += __shfl_xor(tp, 16, 32);
        t2s[g][kk] = tp;            // lanes n and n^16 write identical value
    }
    {
        float4 ta = *(const float4*)&t2s[g][0];
        float4 tb = *(const float4*)&t2s[g][4];
        float4 tc = *(const float4*)&t2s[g][8];
        float4 td = *(const float4*)&t2s[g][12];
        float t2v[16] = {ta.x, ta.y, ta.z, ta.w, tb.x, tb.y, tb.z, tb.w,
                         tc.x, tc.y, tc.z, tc.w, td.x, td.y, td.z, td.w};
        #pragma unroll
        for (int k = 0; k < 16; ++k) {
            const float* wr = &w2[k * 32];
            float v = t2v[k];
            #pragma unroll
            for (int j = 0; j < 16; ++j) v = fmaf(wr[j], m1[j], v);
            m2[k] = fmaxf(v, 0.0f) * dw;
        }
    }
    #pragma unroll
    for (int k = 0; k < 16; ++k) {
        float v = m2[k];
        v = fmaxf(v, __shfl_xor(v, 16, 32));
        v = max_ror<ROR8>(v); v = max_ror<ROR4>(v);
        v = max_ror<ROR2>(v); v = max_ror<ROR1>(v);
        mp2[k] = v;
    }
    // fc3: cooperative mp-term
    {
        const float* wb = &w3[kk * 32 + 16];
        float pa = 0.0f, pb = 0.0f;
        #pragma unroll
        for (int j = 0; j < 8; ++j) pa = fmaf(wb[j], mp2[j], pa);
        #pragma unroll
        for (int j = 0; j < 8; ++j) pb = fmaf(wb[8 + j], mp2[8 + j], pb);
        float tp = (n & 16) ? pb : pa;
        tp += __shfl_xor(tp, 16, 32);
        t2s[g][kk] = tp;
    }
    {
        float4 ta = *(const float4*)&t2s[g][0];
        float4 tb = *(const float4*)&t2s[g][4];
        float4 tc = *(const float4*)&t2s[g][8];
        float4 td = *(const float4*)&t2s[g][12];
        float t3v[16] = {ta.x, ta.y, ta.z, ta.w, tb.x, tb.y, tb.z, tb.w,
                         tc.x, tc.y, tc.z, tc.w, td.x, td.y, td.z, td.w};
        #pragma unroll
        for (int k = 0; k < 16; ++k) {
            const float* wr = &w3[k * 32];
            float v = t3v[k];
            #pragma unroll
            for (int j = 0; j < 16; ++j) v = fmaf(wr[j], m2[j], v);
            m3[k] = fmaxf(v, 0.0f) * dw;
        }
    }

    idxs[g][n] = id;
    {
        const int hi = n >> 3, jj = n & 7;
        unsigned short* base = &m3B[g * 512 + hi * 128 + jj];
        #pragma unroll
        for (int k = 0; k < 16; ++k) {
            const int row = (k + hi + g) & 15;
            base[row * 8] = f2bf(m3[k]);
        }
    }
    __syncthreads();

    // ---- phase 2: feats via MFMA (2 points per wave), bf16 gathers ----
    const int wv  = t >> 6;
    const int l   = t & 63;
    const int hi2 = l >> 4;
    const int k15 = l & 15;
    const unsigned short* xb = xTB + (size_t)b * N_ * 64;

    for (int pp = 0; pp < 2; ++pp) {
        const int p = wv * 2 + pp;

        int ids8[8];
        #pragma unroll
        for (int j = 0; j < 8; ++j) ids8[j] = idxs[p][hi2 * 8 + j];

        const int brow = (k15 + hi2 + p) & 15;
        short8 bfrag = *(const short8*)&m3B[p * 512 + hi2 * 128 + brow * 8];

        f32x4a acc[4];
        #pragma unroll
        for (int ct = 0; ct < 4; ++ct) acc[ct] = (f32x4a){0.f, 0.f, 0.f, 0.f};

        #pragma unroll
        for (int ct = 0; ct < 4; ++ct) {
            union { unsigned short u[8]; short8 v; } A;
            #pragma unroll
            for (int j = 0; j < 8; ++j)
                A.u[j] = xb[((size_t)ids8[j] << 6) + ct * 16 + k15];
            acc[ct] = __builtin_amdgcn_mfma_f32_16x16x32_bf16(A.v, bfrag, acc[ct], 0, 0, 0);
        }

        // acc[ct][r] = feats[c = ct*16 + hi2*4 + r][k = k15]; store k-major
        unsigned short* fb = featsB
            + ((size_t)b * S_chunk + (size_t)blockIdx.x * 8 + p) * 1024;
        #pragma unroll
        for (int ct = 0; ct < 4; ++ct) {
            uint2 val;
            val.x = pack2bf(acc[ct][0], acc[ct][1]);
            val.y = pack2bf(acc[ct][2], acc[ct][3]);
            *(uint2*)&fb[k15 * 64 + ct * 16 + hi2 * 4] = val;
        }
    }
}

// ---------------------------------------------------------------------------
// Kernel C: out = wcvB[64][1024] x featsB[s][1024]^T via bf16 MFMA.
// ---------------------------------------------------------------------------
__global__ __launch_bounds__(512) void fka_out_mfma(
    const unsigned short* __restrict__ wcvB,
    const unsigned short* __restrict__ featsB,
    const float* __restrict__ sup,
    float* __restrict__ out, int s_base, int S_chunk)
{
    const int b    = blockIdx.y;
    const int t    = threadIdx.x;
    const int wv   = t >> 6;
    const int wv_o = wv & 1;
    const int wv_s = wv >> 1;
    const int l    = t & 63;
    const int l15  = l & 15;
    const int lq   = l >> 4;
    const int kq   = lq * 8;

    const unsigned short* ap = wcvB + (size_t)(wv_o * 32 + l15) * 1024 + kq;
    const unsigned short* bp = featsB
        + ((size_t)b * S_chunk + (size_t)blockIdx.x * 128 + wv_s * 32 + l15) * 1024 + kq;

    f32x4a acc[2][2];
    #pragma unroll
    for (int i = 0; i < 2; ++i)
        #pragma unroll
        for (int j = 0; j < 2; ++j) acc[i][j] = (f32x4a){0.f, 0.f, 0.f, 0.f};

    #pragma unroll 4
    for (int ks = 0; ks < 32; ++ks) {
        const int k0 = ks * 32;
        short8 a0 = *(const short8*)(ap + k0);
        short8 a1 = *(const short8*)(ap + 16 * 1024 + k0);
        short8 b0 = *(const short8*)(bp + k0);
        short8 b1 = *(const short8*)(bp + 16 * 1024 + k0);
        acc[0][0] = __builtin_amdgcn_mfma_f32_16x16x32_bf16(a0, b0, acc[0][0], 0, 0, 0);
        acc[0][1] = __builtin_amdgcn_mfma_f32_16x16x32_bf16(a0, b1, acc[0][1], 0, 0, 0);
        acc[1][0] = __builtin_amdgcn_mfma_f32_16x16x32_bf16(a1, b0, acc[1][0], 0, 0, 0);
        acc[1][1] = __builtin_amdgcn_mfma_f32_16x16x32_bf16(a1, b1, acc[1][1], 0, 0, 0);
    }

    #pragma unroll
    for (int sc = 0; sc < 2; ++sc) {
        const int s = s_base + blockIdx.x * 128 + wv_s * 32 + sc * 16 + l15;
        const bool infs = isinf(sup[(size_t)b * 3 * S_ + s]);
        #pragma unroll
        for (int oc = 0; oc < 2; ++oc)
            #pragma unroll
            for (int r = 0; r < 4; ++r) {
                const int o = wv_o * 32 + oc * 16 + lq * 4 + r;
                out[((size_t)b * COUT_ + o) * S_ + s] = infs ? INFINITY : acc[oc][sc][r];
            }
    }
}

// ---------------------------------------------------------------------------
extern "C" void kernel_launch(void* const* d_in, const int* in_sizes, int n_in,
                              void* d_out, int out_size, void* d_ws, size_t ws_size,
                              hipStream_t stream)
{
    const float* x   = (const float*)d_in[0];
    const float* pos = (const float*)d_in[1];
    const float* sup = (const float*)d_in[2];
    const int*   nbr = (const int*)d_in[3];
    const float* rad = (const float*)d_in[4];
    const float* w1  = (const float*)d_in[5];
    const float* w2  = (const float*)d_in[6];
    const float* w3  = (const float*)d_in[7];
    const float* wcv = (const float*)d_in[8];
    float* out = (float*)d_out;

    char* p = (char*)d_ws;
    unsigned short* xTB = (unsigned short*)p;  p += (size_t)B_ * N_ * 64 * sizeof(unsigned short);
    float* posT = (float*)p;                   p += (size_t)B_ * N_ * 4 * sizeof(float);
    unsigned short* wcvB = (unsigned short*)p; p += (size_t)COUT_ * 1024 * sizeof(unsigned short);
    unsigned short* featsB = (unsigned short*)p;
    const size_t used = (size_t)(p - (char*)d_ws);
    const size_t avail = (ws_size > used) ? (ws_size - used) : 0;

    int S_chunk = S_;
    while (S_chunk > 128 && (size_t)B_ * (size_t)S_chunk * 1024 * 2 > avail)
        S_chunk >>= 1;

    transpose_x_kernel<<<dim3(N_ / 64, B_), 256, 0, stream>>>(x, xTB);
    post_kernel<<<dim3(N_ / 256, B_), 256, 0, stream>>>(pos, posT);
    wcvb_kernel<<<dim3(256), 256, 0, stream>>>(wcv, wcvB);

    for (int sb = 0; sb < S_; sb += S_chunk) {
        fka_feats_kernel<<<dim3(S_chunk / 8, B_), 256, 0, stream>>>(
            posT, sup, nbr, rad, w1, w2, w3, xTB, featsB, sb, S_chunk);
        fka_out_mfma<<<dim3(S_chunk / 128, B_), 512, 0, stream>>>(
            wcvB, featsB, sup, out, sb, S_chunk);
    }
}

// Round 9
// 80.800 us; speedup vs baseline: 1.7100x; 1.2229x over previous
//
#include <hip/hip_runtime.h>
#include <math.h>

#define B_    4
#define CIN_  64
#define COUT_ 64
#define N_    32768
#define S_    8192

typedef __attribute__((ext_vector_type(8))) short short8;
typedef __attribute__((ext_vector_type(4))) float f32x4a;

static __device__ __forceinline__ unsigned short f2bf(float x) {
    unsigned u = __float_as_uint(x);
    u += 0x7fffu + ((u >> 16) & 1u);
    return (unsigned short)(u >> 16);
}
static __device__ __forceinline__ unsigned pack2bf(float a, float b) {
    return (unsigned)f2bf(a) | ((unsigned)f2bf(b) << 16);
}
template <int CTRL>
static __device__ __forceinline__ float max_ror(float v) {
    float r = __int_as_float(__builtin_amdgcn_update_dpp(
        __float_as_int(v), __float_as_int(v), CTRL, 0xf, 0xf, false));
    return fmaxf(v, r);
}
#define ROR8 0x128
#define ROR4 0x124
#define ROR2 0x122
#define ROR1 0x121

// feats LDS swizzle: row p (2048B rows), col = byte offset (bf16, k-major
// idx = k*64+c). Masks hit bits 4-6 only -> 8B writes / 16B reads intact.
static __device__ __forceinline__ int fl(int p, int col) {
    return p * 2048 + (col ^ ((p & 7) << 4) ^ (((col >> 7) & 3) << 5));
}

// ---------------------------------------------------------------------------
// Kernel A1: transpose x [B][64][N] f32 -> xTB [B][N][64] bf16
// ---------------------------------------------------------------------------
__global__ __launch_bounds__(256) void transpose_x_kernel(
    const float* __restrict__ x, unsigned short* __restrict__ xTB)
{
    __shared__ float tile[64][65];
    const int b  = blockIdx.y;
    const int n0 = blockIdx.x * 64;
    const int tx = threadIdx.x & 63;
    const int ty = threadIdx.x >> 6;

    const float* xb = x + (size_t)b * CIN_ * N_;
    #pragma unroll
    for (int c = ty; c < 64; c += 4)
        tile[c][tx] = xb[(size_t)c * N_ + n0 + tx];
    __syncthreads();

    const int cp = threadIdx.x & 31;
    const int r0 = threadIdx.x >> 5;
    unsigned short* xTb = xTB + ((size_t)b * N_ + n0) * 64;
    #pragma unroll
    for (int nn = r0; nn < 64; nn += 8) {
        ushort2 v;
        v.x = f2bf(tile[2 * cp][nn]);
        v.y = f2bf(tile[2 * cp + 1][nn]);
        *(ushort2*)&xTb[(size_t)nn * 64 + 2 * cp] = v;
    }
}

// ---------------------------------------------------------------------------
// Kernel A2: pos [B][3][N] -> posT [B][N][4]
// ---------------------------------------------------------------------------
__global__ __launch_bounds__(256) void post_kernel(
    const float* __restrict__ pos, float* __restrict__ posT)
{
    const int b = blockIdx.y;
    const int n = blockIdx.x * 256 + threadIdx.x;
    const float* pb = pos + (size_t)b * 3 * N_;
    float4 v = make_float4(pb[n], pb[N_ + n], pb[2 * N_ + n], 0.0f);
    *(float4*)&posT[((size_t)b * N_ + n) * 4] = v;
}

// ---------------------------------------------------------------------------
// Kernel A3: wcv f32 [o][c][k] -> wcvB bf16 [o][k*64+c]  (k-major)
// ---------------------------------------------------------------------------
__global__ __launch_bounds__(256) void wcvb_kernel(
    const float* __restrict__ wcv, unsigned short* __restrict__ wcvB)
{
    const int i = blockIdx.x * 256 + threadIdx.x;   // over 64*1024
    const int o   = i >> 10;
    const int rem = i & 1023;
    const int k   = rem >> 6;
    const int c   = rem & 63;
    wcvB[i] = f2bf(wcv[(size_t)o * 1024 + c * 16 + k]);
}

// ---------------------------------------------------------------------------
// Fused kernel: 512 threads, 16 points.
//   phase 1: fc pipeline (lane = neighbor), m3 -> LDS B-fragment layout
//   phase 2: feats via MFMA, written to swizzled LDS tile (no HBM round-trip)
//   phase 3: out[64 x 16] = wcvB . feats^T, 8 waves = 4 o-tiles x 2 k-halves
// ---------------------------------------------------------------------------
__global__ __launch_bounds__(512) void fka_fused_kernel(
    const float* __restrict__ posT, const float* __restrict__ sup,
    const int*   __restrict__ nbr, const float* __restrict__ radius,
    const float* __restrict__ w1,  const float* __restrict__ w2,
    const float* __restrict__ w3,  const unsigned short* __restrict__ xTB,
    const unsigned short* __restrict__ wcvB,
    float* __restrict__ out)
{
    __shared__ unsigned short m3B[16 * 512];      // 16KB; reused as pbuf in phase 3
    __shared__ unsigned short featsL[16 * 1024];  // 32KB swizzled feats tile
    __shared__ int   idxs[16][32];
    __shared__ float t2s[16][16];

    const int b  = blockIdx.y;
    const int t  = threadIdx.x;
    const int g  = t >> 5;             // point group 0..15
    const int n  = t & 31;
    const int s0 = blockIdx.x * 16;
    const int s  = s0 + g;

    // ---- phase 1: fc pipeline (lane = neighbor), scalar f32 ----
    const int raw    = nbr[(((size_t)b * S_ + s) << 5) + n];
    const bool valid = raw > -1;
    const int id     = valid ? raw : 0;

    unsigned long long bal = __ballot(valid);
    unsigned bits = (unsigned)(bal >> (t & 32));
    const float nrm = sqrtf((float)__popc(bits));
    float dw = valid ? (1.0f / fmaxf(nrm, 1e-12f)) : 0.0f;

    const float4 pg = *(const float4*)&posT[((size_t)b * N_ + id) * 4];
    float px = pg.x - sup[(size_t)(b * 3 + 0) * S_ + s];
    float py = pg.y - sup[(size_t)(b * 3 + 1) * S_ + s];
    float pz = pg.z - sup[(size_t)(b * 3 + 2) * S_ + s];
    if (isinf(px)) dw = 0.0f;
    px = (isnan(px) || isinf(px)) ? 0.0f : px;
    py = (isnan(py) || isinf(py)) ? 0.0f : py;
    pz = (isnan(pz) || isinf(pz)) ? 0.0f : pz;
    const float inv_r = 1.0f / radius[0];
    px *= inv_r; py *= inv_r; pz *= inv_r;

    const int kk = n & 15;

    float m1[16], mp1[16], m2[16], mp2[16], m3[16];

    #pragma unroll
    for (int k = 0; k < 16; ++k) {
        float v = w1[k * 3 + 0] * px + w1[k * 3 + 1] * py + w1[k * 3 + 2] * pz;
        m1[k] = fmaxf(v, 0.0f) * dw;
    }
    #pragma unroll
    for (int k = 0; k < 16; ++k) {
        float v = m1[k];
        v = fmaxf(v, __shfl_xor(v, 16, 32));
        v = max_ror<ROR8>(v); v = max_ror<ROR4>(v);
        v = max_ror<ROR2>(v); v = max_ror<ROR1>(v);
        mp1[k] = v;
    }
    {
        const float* wb = &w2[kk * 32 + 16];
        float pa = 0.0f, pb = 0.0f;
        #pragma unroll
        for (int j = 0; j < 8; ++j) pa = fmaf(wb[j], mp1[j], pa);
        #pragma unroll
        for (int j = 0; j < 8; ++j) pb = fmaf(wb[8 + j], mp1[8 + j], pb);
        float tp = (n & 16) ? pb : pa;
        tp += __shfl_xor(tp, 16, 32);
        t2s[g][kk] = tp;
    }
    {
        float4 ta = *(const float4*)&t2s[g][0];
        float4 tb = *(const float4*)&t2s[g][4];
        float4 tc = *(const float4*)&t2s[g][8];
        float4 td = *(const float4*)&t2s[g][12];
        float t2v[16] = {ta.x, ta.y, ta.z, ta.w, tb.x, tb.y, tb.z, tb.w,
                         tc.x, tc.y, tc.z, tc.w, td.x, td.y, td.z, td.w};
        #pragma unroll
        for (int k = 0; k < 16; ++k) {
            const float* wr = &w2[k * 32];
            float v = t2v[k];
            #pragma unroll
            for (int j = 0; j < 16; ++j) v = fmaf(wr[j], m1[j], v);
            m2[k] = fmaxf(v, 0.0f) * dw;
        }
    }
    #pragma unroll
    for (int k = 0; k < 16; ++k) {
        float v = m2[k];
        v = fmaxf(v, __shfl_xor(v, 16, 32));
        v = max_ror<ROR8>(v); v = max_ror<ROR4>(v);
        v = max_ror<ROR2>(v); v = max_ror<ROR1>(v);
        mp2[k] = v;
    }
    {
        const float* wb = &w3[kk * 32 + 16];
        float pa = 0.0f, pb = 0.0f;
        #pragma unroll
        for (int j = 0; j < 8; ++j) pa = fmaf(wb[j], mp2[j], pa);
        #pragma unroll
        for (int j = 0; j < 8; ++j) pb = fmaf(wb[8 + j], mp2[8 + j], pb);
        float tp = (n & 16) ? pb : pa;
        tp += __shfl_xor(tp, 16, 32);
        t2s[g][kk] = tp;
    }
    {
        float4 ta = *(const float4*)&t2s[g][0];
        float4 tb = *(const float4*)&t2s[g][4];
        float4 tc = *(const float4*)&t2s[g][8];
        float4 td = *(const float4*)&t2s[g][12];
        float t3v[16] = {ta.x, ta.y, ta.z, ta.w, tb.x, tb.y, tb.z, tb.w,
                         tc.x, tc.y, tc.z, tc.w, td.x, td.y, td.z, td.w};
        #pragma unroll
        for (int k = 0; k < 16; ++k) {
            const float* wr = &w3[k * 32];
            float v = t3v[k];
            #pragma unroll
            for (int j = 0; j < 16; ++j) v = fmaf(wr[j], m2[j], v);
            m3[k] = fmaxf(v, 0.0f) * dw;
        }
    }

    idxs[g][n] = id;
    {
        const int hi = n >> 3, jj = n & 7;
        unsigned short* base = &m3B[g * 512 + hi * 128 + jj];
        #pragma unroll
        for (int k = 0; k < 16; ++k) {
            const int row = (k + hi + g) & 15;
            base[row * 8] = f2bf(m3[k]);
        }
    }
    __syncthreads();

    // ---- phase 2: feats via MFMA (2 points per wave), into swizzled LDS ----
    const int wv  = t >> 6;            // wave 0..7
    const int l   = t & 63;
    const int hi2 = l >> 4;
    const int k15 = l & 15;
    const unsigned short* xb = xTB + (size_t)b * N_ * 64;
    char* fLp = (char*)featsL;

    for (int pp = 0; pp < 2; ++pp) {
        const int p = wv * 2 + pp;

        int ids8[8];
        #pragma unroll
        for (int j = 0; j < 8; ++j) ids8[j] = idxs[p][hi2 * 8 + j];

        const int brow = (k15 + hi2 + p) & 15;
        short8 bfrag = *(const short8*)&m3B[p * 512 + hi2 * 128 + brow * 8];

        f32x4a acc[4];
        #pragma unroll
        for (int ct = 0; ct < 4; ++ct) acc[ct] = (f32x4a){0.f, 0.f, 0.f, 0.f};

        #pragma unroll
        for (int ct = 0; ct < 4; ++ct) {
            union { unsigned short u[8]; short8 v; } A;
            #pragma unroll
            for (int j = 0; j < 8; ++j)
                A.u[j] = xb[((size_t)ids8[j] << 6) + ct * 16 + k15];
            acc[ct] = __builtin_amdgcn_mfma_f32_16x16x32_bf16(A.v, bfrag, acc[ct], 0, 0, 0);
        }

        // acc[ct][r] = feats[c = ct*16 + hi2*4 + r][k = k15]; k-major idx = k*64+c
        #pragma unroll
        for (int ct = 0; ct < 4; ++ct) {
            uint2 val;
            val.x = pack2bf(acc[ct][0], acc[ct][1]);
            val.y = pack2bf(acc[ct][2], acc[ct][3]);
            const int col = k15 * 128 + ct * 32 + hi2 * 8;
            *(uint2*)(fLp + fl(p, col)) = val;
        }
    }
    __syncthreads();

    // ---- phase 3: out tile 64 x 16. wave = (o-tile 0..3, k-half 0..1) ----
    const int ot  = wv & 3;
    const int kh  = wv >> 2;
    const int lq  = hi2;
    const int l15 = k15;

    const unsigned short* apod =
        wcvB + (size_t)(ot * 16 + l15) * 1024 + kh * 512 + lq * 8;

    f32x4a oacc = (f32x4a){0.f, 0.f, 0.f, 0.f};
    #pragma unroll 4
    for (int ks = 0; ks < 16; ++ks) {
        const int col = kh * 1024 + ks * 64 + lq * 16;
        short8 bf = *(const short8*)(fLp + fl(l15, col));
        short8 af = *(const short8*)(apod + ks * 32);
        oacc = __builtin_amdgcn_mfma_f32_16x16x32_bf16(af, bf, oacc, 0, 0, 0);
    }

    float* pbuf = (float*)m3B;    // 4 tiles x 256 floats = 4KB (fits in m3B)
    if (kh == 1) {
        #pragma unroll
        for (int r = 0; r < 4; ++r)
            pbuf[ot * 256 + (lq * 4 + r) * 16 + l15] = oacc[r];
    }
    __syncthreads();
    if (kh == 0) {
        const int sidx = s0 + l15;
        const bool infs = isinf(sup[(size_t)b * 3 * S_ + sidx]);
        #pragma unroll
        for (int r = 0; r < 4; ++r) {
            const float v = oacc[r] + pbuf[ot * 256 + (lq * 4 + r) * 16 + l15];
            const int o = ot * 16 + lq * 4 + r;
            out[((size_t)b * COUT_ + o) * S_ + sidx] = infs ? INFINITY : v;
        }
    }
}

// ---------------------------------------------------------------------------
extern "C" void kernel_launch(void* const* d_in, const int* in_sizes, int n_in,
                              void* d_out, int out_size, void* d_ws, size_t ws_size,
                              hipStream_t stream)
{
    const float* x   = (const float*)d_in[0];
    const float* pos = (const float*)d_in[1];
    const float* sup = (const float*)d_in[2];
    const int*   nbr = (const int*)d_in[3];
    const float* rad = (const float*)d_in[4];
    const float* w1  = (const float*)d_in[5];
    const float* w2  = (const float*)d_in[6];
    const float* w3  = (const float*)d_in[7];
    const float* wcv = (const float*)d_in[8];
    float* out = (float*)d_out;

    char* p = (char*)d_ws;
    unsigned short* xTB = (unsigned short*)p;  p += (size_t)B_ * N_ * 64 * sizeof(unsigned short);
    float* posT = (float*)p;                   p += (size_t)B_ * N_ * 4 * sizeof(float);
    unsigned short* wcvB = (unsigned short*)p; p += (size_t)COUT_ * 1024 * sizeof(unsigned short);

    transpose_x_kernel<<<dim3(N_ / 64, B_), 256, 0, stream>>>(x, xTB);
    post_kernel<<<dim3(N_ / 256, B_), 256, 0, stream>>>(pos, posT);
    wcvb_kernel<<<dim3(256), 256, 0, stream>>>(wcv, wcvB);

    fka_fused_kernel<<<dim3(S_ / 16, B_), 512, 0, stream>>>(
        posT, sup, nbr, rad, w1, w2, w3, xTB, wcvB, out);
}